// Round 2
// baseline (48.734 us; speedup 1.0000x reference)
//
#include <hip/hip_runtime.h>

#define EPS 1e-6f
constexpr int B = 16, C = 26, H = 256, W = 256;
constexpr int CHW  = C * H * W;   // 1,703,936
constexpr int CHW4 = CHW / 4;     // 425,984 float4s per batch
constexpr int HW2  = 2 * H * W;   // 131,072
constexpr int P = 20, K = 2, E = 26;
constexpr int NBPB = 208;         // focal blocks per batch
constexpr int ITER = 8;           // per-thread float4 iterations
constexpr int STRIDE = NBPB * 256;  // 53,248
static_assert(STRIDE * ITER == CHW4, "exact tiling");

__device__ inline float waveReduceSum(float v) {
#pragma unroll
  for (int o = 32; o > 0; o >>= 1) v += __shfl_down(v, o, 64);
  return v;
}

__device__ inline float halfReduceSum(float v) {  // width-32 reduce
#pragma unroll
  for (int o = 16; o > 0; o >>= 1) v += __shfl_xor(v, o, 32);
  return v;
}

// ---------------- Kernel 1: focal-loss partial reduction ----------------
// grid (NBPB, B) x 256. All 16 loads staged to regs first (max MLP), then
// branchless compute: exactly one exp + one rcp + one log per element.
__global__ __launch_bounds__(256) void focal_partial_kernel(
    const float4* __restrict__ pred, const float4* __restrict__ gt,
    float* __restrict__ partials) {
  const int b = blockIdx.y;
  const float4* pp = pred + (size_t)b * CHW4;
  const float4* gg = gt + (size_t)b * CHW4;
  const int i0 = blockIdx.x * 256 + threadIdx.x;

  float4 xs[ITER], gs[ITER];
#pragma unroll
  for (int it = 0; it < ITER; ++it) {
    xs[it] = pp[i0 + it * STRIDE];
    gs[it] = gg[i0 + it * STRIDE];
  }

  float pl = 0.f, nl = 0.f, npos = 0.f;
#pragma unroll
  for (int it = 0; it < ITER; ++it) {
    float xv[4] = {xs[it].x, xs[it].y, xs[it].z, xs[it].w};
    float gv[4] = {gs[it].x, gs[it].y, gs[it].z, gs[it].w};
#pragma unroll
    for (int j = 0; j < 4; ++j) {
      float x = xv[j], g = gv[j];
      float p = __builtin_amdgcn_rcpf(1.f + __expf(-x));
      bool pos = (g == 1.0f);
      float og = 1.f - g;
      float og2 = og * og;
      float omp = 1.f - p;
      // neg weight (1-g)^4 is 0 at g==1, so one selected log serves both paths
      float arg = pos ? (p + EPS) : (1.f - p + EPS);
      float w   = pos ? (omp * omp) : (p * p * (og2 * og2));
      float lw  = __logf(arg) * w;
      pl   += pos ? lw : 0.f;
      nl   += pos ? 0.f : lw;
      npos += pos ? 1.f : 0.f;
    }
  }

  pl = waveReduceSum(pl);
  nl = waveReduceSum(nl);
  npos = waveReduceSum(npos);
  __shared__ float s[3][4];
  int wave = threadIdx.x >> 6, lane = threadIdx.x & 63;
  if (lane == 0) { s[0][wave] = pl; s[1][wave] = nl; s[2][wave] = npos; }
  __syncthreads();
  if (threadIdx.x == 0) {
    float* o = partials + ((size_t)b * NBPB + blockIdx.x) * 4;
    o[0] = s[0][0] + s[0][1] + s[0][2] + s[0][3];
    o[1] = s[1][0] + s[1][1] + s[1][2] + s[1][3];
    o[2] = s[2][0] + s[2][1] + s[2][2] + s[2][3];
    o[3] = 0.f;
  }
}

// ---------------- Kernel 2: fused tail (hw + bu + finalize) ----------------
// grid (B) x 256. Phase A: reduce 208 focal partials. Phase B (wave 0): hw
// L1 gather. Phase C: bu tag loss, 2 persons per wave via 32-lane halves.
__global__ __launch_bounds__(256) void tail_kernel(
    const float* __restrict__ partials,
    const float* __restrict__ hw_pred, const float* __restrict__ hw_gt,
    const float* __restrict__ bu_pred, const float* __restrict__ bu_gt,
    float* __restrict__ out) {
  const int b = blockIdx.x, t = threadIdx.x;
  const int wave = t >> 6, lane = t & 63;
  __shared__ float sA[3][4];
  __shared__ float sHW[2];
  __shared__ float sPP[P], sPV[P];

  // ---- Phase A: focal partial reduction (threads 0..207 active) ----
  float pl = 0.f, nl = 0.f, np = 0.f;
  if (t < NBPB) {
    const float* o = partials + ((size_t)b * NBPB + t) * 4;
    pl = o[0]; nl = o[1]; np = o[2];
  }
  pl = waveReduceSum(pl);
  nl = waveReduceSum(nl);
  np = waveReduceSum(np);
  if (lane == 0) { sA[0][wave] = pl; sA[1][wave] = nl; sA[2][wave] = np; }

  // ---- Phase B: hw reg-L1 (wave 0, lanes 0..39) ----
  if (wave == 0) {
    float contrib = 0.f;
    bool wv = false;
    if (lane < P * K) {
      const float* g3 = hw_gt + ((size_t)(b * P * K + lane)) * 3;
      float val = g3[0];
      int idx = (int)g3[1];
      wv = g3[2] > 0.f;
      float gvv = hw_pred[(size_t)b * HW2 + idx];
      contrib = wv ? fabsf(gvv - val) : 0.f;
    }
    unsigned long long m = __ballot(wv);
    float l1 = waveReduceSum(contrib);
    if (lane == 0) {
      unsigned long long mm = (m | (m >> 1)) & 0x5555555555ULL;
      sHW[0] = l1;
      sHW[1] = (float)__popcll(mm);
    }
  }

  // ---- Phase C: bu tag loss, persons p = pbase + wave*2 + half ----
  const int half = lane >> 5, l = lane & 31;
  for (int pbase = 0; pbase < P; pbase += 8) {
    int p = pbase + wave * 2 + half;
    float plp = 0.f, nlp = 0.f, npp = 0.f;
    bool mv = false;
    if (p < P && l < E) {
      const float* g3 = bu_gt + ((size_t)((b * P + p) * E + l)) * 3;
      float val = g3[0];
      int idx = (int)g3[1];
      mv = g3[2] > 0.f;
      float x = bu_pred[(size_t)b * CHW + idx];
      float gv = __builtin_amdgcn_rcpf(1.f + __expf(-x));
      if (mv) {
        if (val == 1.0f) {
          float o = 1.f - gv;
          plp = __logf(gv + EPS) * o * o;
          npp = 1.f;
        } else {
          nlp = __logf(1.f - gv + EPS) * gv * gv;
        }
      }
    }
    plp = halfReduceSum(plp);
    nlp = halfReduceSum(nlp);
    npp = halfReduceSum(npp);
    unsigned long long m = __ballot(mv);
    bool any = half ? ((m >> 32) != 0ULL) : ((m & 0xffffffffULL) != 0ULL);
    if (l == 0 && p < P) {
      float per = (npp == 0.f) ? -nlp : -(plp + nlp);
      float pv = any ? 1.f : 0.f;
      sPP[p] = per * pv;
      sPV[p] = pv;
    }
  }

  __syncthreads();
  if (t == 0) {
    float PL = sA[0][0] + sA[0][1] + sA[0][2] + sA[0][3];
    float NL = sA[1][0] + sA[1][1] + sA[1][2] + sA[1][3];
    float NP = sA[2][0] + sA[2][1] + sA[2][2] + sA[2][3];
    float hm = (NP > 0.f) ? (-(PL + NL) / fmaxf(NP, 1.f)) : -NL;
    out[b] = hm * 1.0f;  // HM_FACTOR
    float l1 = sHW[0], npe = sHW[1];
    out[16 + b] = ((npe > 0.f) ? l1 / fmaxf(npe, 1.f) : 0.f) * 0.1f;  // HW_FACTOR
    float spp = 0.f, spv = 0.f;
#pragma unroll
    for (int i = 0; i < P; ++i) { spp += sPP[i]; spv += sPV[i]; }
    out[32 + b] = (spp / fmaxf(spv, 1.f)) * 1.0f;  // BU_FACTOR
  }
}

extern "C" void kernel_launch(void* const* d_in, const int* in_sizes, int n_in,
                              void* d_out, int out_size, void* d_ws, size_t ws_size,
                              hipStream_t stream) {
  const float* hm_pred = (const float*)d_in[0];
  const float* hm_gt   = (const float*)d_in[1];
  const float* hw_pred = (const float*)d_in[2];
  const float* hw_gt   = (const float*)d_in[3];
  const float* bu_pred = (const float*)d_in[4];
  const float* bu_gt   = (const float*)d_in[5];
  float* out = (float*)d_out;

  float* partials = (float*)d_ws;  // B*NBPB*4 = 13,312 floats

  hipLaunchKernelGGL(focal_partial_kernel, dim3(NBPB, B), dim3(256), 0, stream,
                     (const float4*)hm_pred, (const float4*)hm_gt, partials);
  hipLaunchKernelGGL(tail_kernel, dim3(B), dim3(256), 0, stream,
                     partials, hw_pred, hw_gt, bu_pred, bu_gt, out);
}

// Round 4
// 45.703 us; speedup vs baseline: 1.0663x; 1.0663x over previous
//
#include <hip/hip_runtime.h>

#define EPS 1e-6f
constexpr int B = 16, C = 26, H = 256, W = 256;
constexpr int CHW  = C * H * W;   // 1,703,936
constexpr int CHW4 = CHW / 4;     // 425,984 float4s per batch
constexpr int HW2  = 2 * H * W;   // 131,072
constexpr int P = 20, K = 2, E = 26;
constexpr int NBPB = 128;         // focal blocks per batch -> grid 2048 = 8/CU exactly
constexpr int ITER = 13;          // per-thread float4 iterations
constexpr int CHUNK = ITER * 256; // 3328 float4s per block (52 KB per stream)
static_assert(NBPB * CHUNK == CHW4, "exact tiling");

typedef float f32x4 __attribute__((ext_vector_type(4)));

__device__ inline float waveReduceSum(float v) {
#pragma unroll
  for (int o = 32; o > 0; o >>= 1) v += __shfl_down(v, o, 64);
  return v;
}

__device__ inline float halfReduceSum(float v) {  // width-32 reduce
#pragma unroll
  for (int o = 16; o > 0; o >>= 1) v += __shfl_xor(v, o, 32);
  return v;
}

// ---------------- Kernel 1: focal-loss partial reduction ----------------
// grid (NBPB, B) x 256. Block owns a contiguous CHUNK of float4s; depth-2
// software-pipelined loads; gt stream loaded nontemporal (evict-first) so
// pred stays L3-resident across graph replays.
__global__ __launch_bounds__(256) void focal_partial_kernel(
    const f32x4* __restrict__ pred, const f32x4* __restrict__ gt,
    float* __restrict__ partials) {
  const int b = blockIdx.y;
  const size_t base = (size_t)b * CHW4 + (size_t)blockIdx.x * CHUNK;
  const f32x4* pp = pred + base;
  const f32x4* gg = gt + base;
  const int tid = threadIdx.x;

  f32x4 xc = pp[tid];
  f32x4 gc = __builtin_nontemporal_load(gg + tid);

  float pl = 0.f, nl = 0.f, npos = 0.f;
#pragma unroll
  for (int it = 0; it < ITER; ++it) {
    f32x4 xn, gn;
    if (it + 1 < ITER) {
      xn = pp[(it + 1) * 256 + tid];
      gn = __builtin_nontemporal_load(gg + (it + 1) * 256 + tid);
    }
#pragma unroll
    for (int j = 0; j < 4; ++j) {
      float x = xc[j], g = gc[j];
      float p = __builtin_amdgcn_rcpf(1.f + __expf(-x));
      bool pos = (g == 1.0f);
      float og = 1.f - g;
      float og2 = og * og;
      float omp = 1.f - p;
      // neg weight (1-g)^4 is 0 at g==1, so one selected log serves both paths
      float arg = pos ? (p + EPS) : (1.f - p + EPS);
      float w   = pos ? (omp * omp) : (p * p * (og2 * og2));
      float lw  = __logf(arg) * w;
      pl   += pos ? lw : 0.f;
      nl   += pos ? 0.f : lw;
      npos += pos ? 1.f : 0.f;
    }
    if (it + 1 < ITER) { xc = xn; gc = gn; }
  }

  pl = waveReduceSum(pl);
  nl = waveReduceSum(nl);
  npos = waveReduceSum(npos);
  __shared__ float s[3][4];
  int wave = threadIdx.x >> 6, lane = threadIdx.x & 63;
  if (lane == 0) { s[0][wave] = pl; s[1][wave] = nl; s[2][wave] = npos; }
  __syncthreads();
  if (threadIdx.x == 0) {
    float* o = partials + ((size_t)b * NBPB + blockIdx.x) * 4;
    o[0] = s[0][0] + s[0][1] + s[0][2] + s[0][3];
    o[1] = s[1][0] + s[1][1] + s[1][2] + s[1][3];
    o[2] = s[2][0] + s[2][1] + s[2][2] + s[2][3];
    o[3] = 0.f;
  }
}

// ---------------- Kernel 2: fused tail (hw + bu + finalize) ----------------
// grid (B) x 256. Phase A: reduce NBPB focal partials. Phase B (wave 0): hw
// L1 gather. Phase C: bu tag loss, 2 persons per wave via 32-lane halves.
__global__ __launch_bounds__(256) void tail_kernel(
    const float* __restrict__ partials,
    const float* __restrict__ hw_pred, const float* __restrict__ hw_gt,
    const float* __restrict__ bu_pred, const float* __restrict__ bu_gt,
    float* __restrict__ out) {
  const int b = blockIdx.x, t = threadIdx.x;
  const int wave = t >> 6, lane = t & 63;
  __shared__ float sA[3][4];
  __shared__ float sHW[2];
  __shared__ float sPP[P], sPV[P];

  // ---- Phase A: focal partial reduction (threads 0..NBPB-1 active) ----
  float pl = 0.f, nl = 0.f, np = 0.f;
  if (t < NBPB) {
    const float* o = partials + ((size_t)b * NBPB + t) * 4;
    pl = o[0]; nl = o[1]; np = o[2];
  }
  pl = waveReduceSum(pl);
  nl = waveReduceSum(nl);
  np = waveReduceSum(np);
  if (lane == 0) { sA[0][wave] = pl; sA[1][wave] = nl; sA[2][wave] = np; }

  // ---- Phase B: hw reg-L1 (wave 0, lanes 0..39) ----
  if (wave == 0) {
    float contrib = 0.f;
    bool wv = false;
    if (lane < P * K) {
      const float* g3 = hw_gt + ((size_t)(b * P * K + lane)) * 3;
      float val = g3[0];
      int idx = (int)g3[1];
      wv = g3[2] > 0.f;
      float gvv = hw_pred[(size_t)b * HW2 + idx];
      contrib = wv ? fabsf(gvv - val) : 0.f;
    }
    unsigned long long m = __ballot(wv);
    float l1 = waveReduceSum(contrib);
    if (lane == 0) {
      unsigned long long mm = (m | (m >> 1)) & 0x5555555555ULL;
      sHW[0] = l1;
      sHW[1] = (float)__popcll(mm);
    }
  }

  // ---- Phase C: bu tag loss, persons p = pbase + wave*2 + half ----
  const int half = lane >> 5, l = lane & 31;
  for (int pbase = 0; pbase < P; pbase += 8) {
    int p = pbase + wave * 2 + half;
    float plp = 0.f, nlp = 0.f, npp = 0.f;
    bool mv = false;
    if (p < P && l < E) {
      const float* g3 = bu_gt + ((size_t)((b * P + p) * E + l)) * 3;
      float val = g3[0];
      int idx = (int)g3[1];
      mv = g3[2] > 0.f;
      float x = bu_pred[(size_t)b * CHW + idx];
      float gv = __builtin_amdgcn_rcpf(1.f + __expf(-x));
      if (mv) {
        if (val == 1.0f) {
          float o = 1.f - gv;
          plp = __logf(gv + EPS) * o * o;
          npp = 1.f;
        } else {
          nlp = __logf(1.f - gv + EPS) * gv * gv;
        }
      }
    }
    plp = halfReduceSum(plp);
    nlp = halfReduceSum(nlp);
    npp = halfReduceSum(npp);
    unsigned long long m = __ballot(mv);
    bool any = half ? ((m >> 32) != 0ULL) : ((m & 0xffffffffULL) != 0ULL);
    if (l == 0 && p < P) {
      float per = (npp == 0.f) ? -nlp : -(plp + nlp);
      float pv = any ? 1.f : 0.f;
      sPP[p] = per * pv;
      sPV[p] = pv;
    }
  }

  __syncthreads();
  if (t == 0) {
    float PL = sA[0][0] + sA[0][1] + sA[0][2] + sA[0][3];
    float NL = sA[1][0] + sA[1][1] + sA[1][2] + sA[1][3];
    float NP = sA[2][0] + sA[2][1] + sA[2][2] + sA[2][3];
    float hm = (NP > 0.f) ? (-(PL + NL) / fmaxf(NP, 1.f)) : -NL;
    out[b] = hm * 1.0f;  // HM_FACTOR
    float l1 = sHW[0], npe = sHW[1];
    out[16 + b] = ((npe > 0.f) ? l1 / fmaxf(npe, 1.f) : 0.f) * 0.1f;  // HW_FACTOR
    float spp = 0.f, spv = 0.f;
#pragma unroll
    for (int i = 0; i < P; ++i) { spp += sPP[i]; spv += sPV[i]; }
    out[32 + b] = (spp / fmaxf(spv, 1.f)) * 1.0f;  // BU_FACTOR
  }
}

extern "C" void kernel_launch(void* const* d_in, const int* in_sizes, int n_in,
                              void* d_out, int out_size, void* d_ws, size_t ws_size,
                              hipStream_t stream) {
  const float* hm_pred = (const float*)d_in[0];
  const float* hm_gt   = (const float*)d_in[1];
  const float* hw_pred = (const float*)d_in[2];
  const float* hw_gt   = (const float*)d_in[3];
  const float* bu_pred = (const float*)d_in[4];
  const float* bu_gt   = (const float*)d_in[5];
  float* out = (float*)d_out;

  float* partials = (float*)d_ws;  // B*NBPB*4 = 8192 floats

  hipLaunchKernelGGL(focal_partial_kernel, dim3(NBPB, B), dim3(256), 0, stream,
                     (const f32x4*)hm_pred, (const f32x4*)hm_gt, partials);
  hipLaunchKernelGGL(tail_kernel, dim3(B), dim3(256), 0, stream,
                     partials, hw_pred, hw_gt, bu_pred, bu_gt, out);
}